// Round 1
// 1003.771 us; speedup vs baseline: 1.1544x; 1.1544x over previous
//
#include <hip/hip_runtime.h>
#include <math.h>

#define G 1024
#define NPG 512
#define NTOT (G*NPG)        // 524288
#define F 256
#define EDGES 8388608
#define EPG (EDGES/G)       // 8192 edges per graph, contiguous
#define KKEEP 256

// output layout (flat float32)
#define O_PX  ((size_t)0)
#define O_EI  ((size_t)67108864)   // G*K*F
#define O_EW  ((size_t)83886080)   // + 2*E
#define O_NGI ((size_t)92274688)   // + E

typedef float f32x4 __attribute__((ext_vector_type(4)));
typedef int   i32x4 __attribute__((ext_vector_type(4)));

// ---- K1: h[i] = dot(x[i,:], w_gnn)  (one wave per row, float4 loads) ----
// numerics identical to the verified kernel: per-lane dot4 + 64-lane shfl tree
__global__ __launch_bounds__(256) void k_h(const float* __restrict__ x,
                                           const float* __restrict__ w,
                                           float* __restrict__ h) {
    int row  = blockIdx.x * 4 + (threadIdx.x >> 6);
    int lane = threadIdx.x & 63;
    const f32x4* x4 = (const f32x4*)x;
    const f32x4* w4 = (const f32x4*)w;
    f32x4 xv = __builtin_nontemporal_load(&x4[(size_t)row * 64 + lane]);
    f32x4 wv = w4[lane];
    float s = xv[0]*wv[0] + xv[1]*wv[1] + xv[2]*wv[2] + xv[3]*wv[3];
    #pragma unroll
    for (int off = 32; off > 0; off >>= 1) s += __shfl_down(s, off, 64);
    if (lane == 0) h[row] = s;
}

// ---- K2: per-graph: edge-ordered aggregation + tanh + top-K sort + outputs ----
// LDS budget: hloc 2K + cursor 2K + c_arr 32K + slot 16K (+wsum) = 52 KB -> 3 blocks/CU
// cnt (u32[512]) and keys (u64[512]) overlay the slot region (dead ranges don't overlap).
__global__ __launch_bounds__(256) void k_agg_topk(
    const float* __restrict__ h,
    const int* __restrict__ src,
    const int* __restrict__ dst,
    const float* __restrict__ ew,
    int* __restrict__ kept,
    float* __restrict__ kscore,
    int* __restrict__ new_id,
    float* __restrict__ out_ngi)
{
    __shared__ float    hloc[NPG];                    // 2 KB
    __shared__ unsigned cursor[NPG];                  // 2 KB
    __shared__ __align__(16) float c_arr[EPG];        // 32 KB
    __shared__ __align__(16) unsigned short slot[EPG];// 16 KB (overlaid by cnt, then keys)
    __shared__ unsigned wsum[4];

    unsigned* cnt            = (unsigned*)slot;            // dead once placement starts
    unsigned long long* keys = (unsigned long long*)slot;  // live only after sum phase

    const int tid = threadIdx.x;
    const int g = blockIdx.x;
    const int base_n = g * NPG;
    const size_t base_e = (size_t)g * EPG;

    for (int i = tid; i < NPG; i += 256) { hloc[i] = h[base_n + i]; cnt[i] = 0; }
    __syncthreads();

    // count in-degree + per-edge contribution c = ew * h[src] (f32 product, matches np)
    #pragma unroll 4
    for (int k = 0; k < EPG/256; ++k) {
        int e = k*256 + tid;
        int s = src[base_e + e] - base_n;
        int d = dst[base_e + e] - base_n;
        c_arr[e] = ew[base_e + e] * hloc[s];
        atomicAdd(&cnt[d], 1u);
    }
    __syncthreads();

    // exclusive scan of cnt -> cursor (2 elems/thread, shfl wave scan, 2 barriers)
    {
        unsigned a = cnt[2*tid], b = cnt[2*tid+1];
        unsigned p = a + b;
        unsigned s = p;
        int lane = tid & 63, wid = tid >> 6;
        #pragma unroll
        for (int off = 1; off < 64; off <<= 1) {
            unsigned v = __shfl_up(s, off, 64);
            if (lane >= off) s += v;
        }
        if (lane == 63) wsum[wid] = s;
        __syncthreads();
        unsigned wo = 0;
        #pragma unroll
        for (int wI = 0; wI < 4; ++wI) if (wI < wid) wo += wsum[wI];
        unsigned excl = s + wo - p;
        cursor[2*tid]   = excl;
        cursor[2*tid+1] = excl + a;
    }
    __syncthreads();

    // CSR placement (arrival order irrelevant — fixed up by sort below).
    // After this pass cursor[d] == inclusive prefix, so start/count derive from cursor.
    #pragma unroll 4
    for (int k = 0; k < EPG/256; ++k) {
        int e = k*256 + tid;
        int d = dst[base_e + e] - base_n;
        unsigned pos = atomicAdd(&cursor[d], 1u);
        slot[pos] = (unsigned short)e;
    }
    __syncthreads();

    // per-node: insertion-sort slot segment (increasing e), then sum in that order
    // -> identical float addition sequence to np.add.at
    float sc_reg[2];
    #pragma unroll
    for (int r = 0; r < 2; ++r) {
        int d  = tid + r*256;
        int s0 = (d > 0) ? (int)cursor[d-1] : 0;
        int e1 = (int)cursor[d];
        for (int i = s0 + 1; i < e1; ++i) {
            unsigned short key = slot[i];
            int j = i - 1;
            while (j >= s0 && slot[j] > key) { slot[j+1] = slot[j]; --j; }
            slot[j+1] = key;
        }
        float ss = 0.0f;
        for (int i = s0; i < e1; ++i) ss += c_arr[slot[i]];
        sc_reg[r] = (float)tanh((double)(ss + hloc[d]));
    }
    __syncthreads();   // all reads of slot/c_arr complete before keys overlay

    // pack keys: (ordered float bits)<<32 | (511 - idx)  -> ascending bitonic sort
    #pragma unroll
    for (int r = 0; r < 2; ++r) {
        int d = tid + r*256;
        unsigned u = __float_as_uint(sc_reg[r]);
        unsigned ord = ((int)u < 0) ? ~u : (u ^ 0x80000000u);
        keys[d] = ((unsigned long long)ord << 32) | (unsigned)(NPG - 1 - d);
    }
    __syncthreads();

    for (int k = 2; k <= NPG; k <<= 1) {
        for (int j = k >> 1; j > 0; j >>= 1) {
            #pragma unroll
            for (int r = 0; r < 2; ++r) {
                int i = tid + r*256;
                int ixj = i ^ j;
                if (ixj > i) {
                    unsigned long long a = keys[i], b = keys[ixj];
                    bool up = ((i & k) == 0);
                    if ((a > b) == up) { keys[i] = b; keys[ixj] = a; }
                }
            }
            __syncthreads();
        }
    }

    // emit verdict for ALL 512 nodes: top-K -> outputs + new id; rest -> new_id = -1
    // (replaces the separate 2 MB memset dispatch)
    #pragma unroll
    for (int r = 0; r < 2; ++r) {
        int i = tid + r*256;                       // rank from the top
        unsigned long long kk = keys[NPG - 1 - i];
        int lidx = NPG - 1 - (int)(kk & 0xFFFFFFFFULL);
        int oldg = base_n + lidx;
        if (r == 0) {                              // i < KKEEP always (KKEEP == 256)
            int nw = g * KKEEP + i;
            unsigned ord = (unsigned)(kk >> 32);
            unsigned u = (ord & 0x80000000u) ? (ord ^ 0x80000000u) : ~ord;
            kept[nw]   = oldg;
            kscore[nw] = __uint_as_float(u);       // exact inverse of the ord mapping
            new_id[oldg] = nw;
            out_ngi[nw] = (float)g;                // ngi[oldg] == g by construction
        } else {
            new_id[oldg] = -1;
        }
    }
}

// ---- K3: pooled_x = x[kept] * score  (2 rows per wave, NT streams) ----
__global__ __launch_bounds__(256) void k_gather(
    const float* __restrict__ x,
    const int* __restrict__ kept,
    const float* __restrict__ kscore,
    float* __restrict__ out_px)
{
    int tid  = threadIdx.x;
    int lane = tid & 63;
    int half = lane >> 5;
    int l    = lane & 31;
    int r    = blockIdx.x * 8 + ((tid >> 6) << 1) + half;
    int old  = kept[r];
    float sc = kscore[r];
    const f32x4* xr = (const f32x4*)x + (size_t)old * 64 + 2*l;
    f32x4 v0 = __builtin_nontemporal_load(xr);
    f32x4 v1 = __builtin_nontemporal_load(xr + 1);
    v0 *= sc; v1 *= sc;
    f32x4* o = (f32x4*)out_px + (size_t)r * 64 + 2*l;
    __builtin_nontemporal_store(v0, o);
    __builtin_nontemporal_store(v1, o + 1);
}

// ---- K4: edge remap + mask, ints written as floats (NT streams) ----
__global__ __launch_bounds__(256) void k_remap(
    const int* __restrict__ src,
    const int* __restrict__ dst,
    const float* __restrict__ ew,
    const int* __restrict__ new_id,
    float* __restrict__ out)
{
    size_t t = (size_t)blockIdx.x * 256 + threadIdx.x;   // one int4/float4 per thread
    i32x4 s = __builtin_nontemporal_load((const i32x4*)src + t);
    i32x4 d = __builtin_nontemporal_load((const i32x4*)dst + t);
    f32x4 w = __builtin_nontemporal_load((const f32x4*)ew + t);
    int ns0 = new_id[s[0]], ns1 = new_id[s[1]], ns2 = new_id[s[2]], ns3 = new_id[s[3]];
    int nd0 = new_id[d[0]], nd1 = new_id[d[1]], nd2 = new_id[d[2]], nd3 = new_id[d[3]];
    bool v0 = (ns0 >= 0) && (nd0 >= 0);
    bool v1 = (ns1 >= 0) && (nd1 >= 0);
    bool v2 = (ns2 >= 0) && (nd2 >= 0);
    bool v3 = (ns3 >= 0) && (nd3 >= 0);
    f32x4 os = { v0 ? (float)ns0 : 0.0f, v1 ? (float)ns1 : 0.0f,
                 v2 ? (float)ns2 : 0.0f, v3 ? (float)ns3 : 0.0f };
    f32x4 od = { v0 ? (float)nd0 : 0.0f, v1 ? (float)nd1 : 0.0f,
                 v2 ? (float)nd2 : 0.0f, v3 ? (float)nd3 : 0.0f };
    f32x4 ow = { v0 ? w[0] : 0.0f, v1 ? w[1] : 0.0f,
                 v2 ? w[2] : 0.0f, v3 ? w[3] : 0.0f };
    __builtin_nontemporal_store(os, (f32x4*)(out + O_EI) + t);
    __builtin_nontemporal_store(od, (f32x4*)(out + O_EI + EDGES) + t);
    __builtin_nontemporal_store(ow, (f32x4*)(out + O_EW) + t);
}

extern "C" void kernel_launch(void* const* d_in, const int* in_sizes, int n_in,
                              void* d_out, int out_size, void* d_ws, size_t ws_size,
                              hipStream_t stream) {
    const float* x   = (const float*)d_in[0];
    const int*   ei  = (const int*)d_in[1];     // [2,E]: row0=src, row1=dst
    const float* ew  = (const float*)d_in[2];
    const float* w   = (const float*)d_in[4];
    float* out = (float*)d_out;

    char* ws = (char*)d_ws;
    float* h      = (float*)(ws);                                  // N f32
    int*   kept   = (int*)  (ws + (size_t)NTOT*4);                 // G*K i32
    float* kscore = (float*)(ws + (size_t)NTOT*4 + (size_t)G*KKEEP*4);
    int*   new_id = (int*)  (ws + (size_t)NTOT*4 + (size_t)G*KKEEP*8);  // N i32

    k_h       <<<NTOT/4,        256, 0, stream>>>(x, w, h);
    k_agg_topk<<<G,             256, 0, stream>>>(h, ei, ei + EDGES, ew,
                                                  kept, kscore, new_id, out + O_NGI);
    k_gather  <<<G*KKEEP/8,     256, 0, stream>>>(x, kept, kscore, out + O_PX);
    k_remap   <<<EDGES/1024,    256, 0, stream>>>(ei, ei + EDGES, ew, new_id, out);
}